// Round 6
// baseline (840.238 us; speedup 1.0000x reference)
//
#include <hip/hip_runtime.h>
#include <math.h>

#define NB 8192     // batch rows
#define DD 512      // hidden dim
#define KC 4096     // codebook size
#define NL 4        // layers

#define NTB 32      // part[] column tiles (128 codes each)
#define MARGIN 4.0f // bf16-dot candidate margin (>> 2*max bf16 dot error ~0.3)

typedef __bf16 bf16x8 __attribute__((ext_vector_type(8)));
typedef float  f32x4  __attribute__((ext_vector_type(4)));
typedef unsigned short u16;

struct Top2 { float v1; int i1; float v2; int i2; };

__device__ __forceinline__ u16 f2bf(float f) {   // RNE fp32 -> bf16
    unsigned u = __float_as_uint(f);
    return (u16)((u + 0x7fffu + ((u >> 16) & 1u)) >> 16);
}

__device__ __forceinline__ void top2_insert(float v, int idx, float& v1, int& i1, float& v2, int& i2) {
    if (v > v1 || (v == v1 && idx < i1)) { v2 = v1; i2 = i1; v1 = v; i1 = idx; }
    else if (v > v2 || (v == v2 && idx < i2)) { v2 = v; i2 = idx; }
}

__device__ __forceinline__ void pick_better(float av, int ai, float bv, int bi, float& ov, int& oi) {
    if (av > bv || (av == bv && ai < bi)) { ov = av; oi = ai; } else { ov = bv; oi = bi; }
}

// fp32 -> bf16 bulk convert (n4 = count/4)
__global__ __launch_bounds__(256)
void k_cvt_bf16(const float* __restrict__ src, u16* __restrict__ dst, int n4)
{
    const int i = blockIdx.x * 256 + threadIdx.x;
    if (i < n4) {
        const float4 f = ((const float4*)src)[i];
        uint2 p;
        p.x = (unsigned)f2bf(f.x) | ((unsigned)f2bf(f.y) << 16);
        p.y = (unsigned)f2bf(f.z) | ((unsigned)f2bf(f.w) << 16);
        ((uint2*)dst)[i] = p;
    }
}

// A-RESIDENT bf16 MFMA GEMM: sim = Rb [NB x DD] @ Cb^T [KC x DD].
// Each block pins a 128-row A panel x full K=512 in LDS (128 KB, loaded once,
// chunk^(r&7) swizzle -> 2-way-free frag reads), then sweeps 4 positions x 256
// codes, streaming B via 2 x 16 KB dbuf ([tile][ks][row][16B] layout, conflict-
// free reads) with register staging 2 steps ahead + single s_barrier per K-step
// (R5-proven ordering). K-chain = 64 steps/block; grid 256 = 1 block/CU.
// Fused per-row top-2 per 128-code tile -> part[NB][32] (same as R2-R5).
__global__ __launch_bounds__(512, 2)
void k_simtop2(const u16* __restrict__ Rb, const u16* __restrict__ Cb,
               Top2* __restrict__ part /* [NB][NTB] */)
{
    extern __shared__ char lds[];          // A: 131072 | B: 2 x 16384 = 163840
    char* ldsA = lds;
    char* ldsB = lds + 131072;

    const int tid  = threadIdx.x;
    const int lane = tid & 63;
    const int w    = tid >> 6;        // 0..7
    const int wm   = w >> 2;          // 0..1  (row half)
    const int wn   = w & 3;           // 0..3  (col quarter of 256-col position)

    const int bid  = blockIdx.x;      // 0..255
    const int pan  = bid & 63;        // row panel; bid%8 ~ XCD -> 4 col-groups of
    const int cgrp = bid >> 6;        // the same pan share one XCD's L2
    const int rb0  = pan * 128;

    // ---- A panel load: 128 rows x 1024 B, store chunk c at c^(r&7)
    for (int it = 0; it < 16; ++it) {
        const int flat = it * 512 + tid;
        const int r = flat >> 6, c = flat & 63;
        const uint4 v = *(const uint4*)((const char*)Rb + (size_t)(rb0 + r) * 1024 + c * 16);
        *(uint4*)(ldsA + r * 1024 + ((c ^ (r & 7)) << 4)) = v;
    }

    // B staging: thread -> (tile btau, row brow, half bh); 2 uint4 per step
    const int btau = tid >> 8;            // 0..1
    const int brow = (tid >> 1) & 127;    // 0..127
    const int bh   = tid & 1;             // ks = 2bh, 2bh+1
    char* bwr = ldsB + btau * 8192 + brow * 16;   // + P*16384 + ks*2048

    // fragment addressing
    const int la = lane & 15, ks = lane >> 4;
    const int xa = la & 7;                           // A chunk xor
    const int arow0 = (wm * 64 + la) * 1024;         // + m*16*1024
    const int tauW  = wn >> 1;
    const int brf   = ((wn & 1) * 64 + la) * 16;     // + n*16*16
    const char* bRd = ldsB + tauW * 8192 + ks * 2048;  // + P*16384 + brf + n*256

    f32x4 acc[4][4];
    const f32x4 zero = {0.f, 0.f, 0.f, 0.f};

    const int rgrp = lane >> 4;
    const int cidx = lane & 15;
    Top2 (*mrg)[4] = (Top2 (*)[4])ldsB;   // epilogue scratch (8 KB, overlaps buf0)

#define BLOAD(r0, r1, T) do { const char* _p = gB + (T) * 64; \
        r0 = *(const uint4*)(_p); r1 = *(const uint4*)(_p + 16); } while (0)

#define ITER(T, r0, r1, P) do {                                           \
        *(uint4*)(bwr + (P) * 16384 + (2 * bh)     * 2048) = r0;          \
        *(uint4*)(bwr + (P) * 16384 + (2 * bh + 1) * 2048) = r1;          \
        if ((T) + 2 < 16) BLOAD(r0, r1, (T) + 2);                         \
        asm volatile("s_waitcnt lgkmcnt(0)" ::: "memory");                \
        __builtin_amdgcn_s_barrier();                                     \
        __builtin_amdgcn_sched_barrier(0);                                \
        bf16x8 av[4], bv[4];                                              \
        _Pragma("unroll")                                                 \
        for (int m = 0; m < 4; ++m)                                       \
            av[m] = *(const bf16x8*)(ldsA + arow0 + m * 16384 +           \
                                     ((((T) * 4 + ks) ^ xa) << 4));       \
        _Pragma("unroll")                                                 \
        for (int n = 0; n < 4; ++n)                                       \
            bv[n] = *(const bf16x8*)(bRd + (P) * 16384 + brf + n * 256);  \
        _Pragma("unroll")                                                 \
        for (int m = 0; m < 4; ++m)                                       \
            _Pragma("unroll")                                             \
            for (int n = 0; n < 4; ++n)                                   \
                acc[m][n] = __builtin_amdgcn_mfma_f32_16x16x32_bf16(av[m], bv[n], acc[m][n], 0, 0, 0); \
    } while (0)

#pragma unroll 1
    for (int p4 = 0; p4 < 4; ++p4) {
        const int code0 = cgrp * 1024 + p4 * 256;      // position's first code
        const char* gB = (const char*)Cb +
            (size_t)(code0 + btau * 128 + brow) * 1024 + bh * 32;

#pragma unroll
        for (int m = 0; m < 4; ++m)
#pragma unroll
            for (int n = 0; n < 4; ++n) acc[m][n] = zero;

        uint4 e0, e1, o0, o1;
        BLOAD(e0, e1, 0);
        BLOAD(o0, o1, 1);

#pragma unroll 1
        for (int t = 0; t < 16; t += 2) {
            ITER(t,     e0, e1, 0);
            ITER(t + 1, o0, o1, 1);
        }

        __syncthreads();   // drain; buf regions now reusable as mrg

        // per-wave top-2 over its 64-code quarter, per row
#pragma unroll
        for (int m = 0; m < 4; ++m) {
#pragma unroll
            for (int j = 0; j < 4; ++j) {
                float v1 = -INFINITY, v2 = -INFINITY;
                int   i1 = 0x7fffffff, i2 = 0x7fffffff;
#pragma unroll
                for (int n = 0; n < 4; ++n)
                    top2_insert(acc[m][n][j], code0 + tauW * 128 + (wn & 1) * 64 + n * 16 + cidx,
                                v1, i1, v2, i2);
                for (int off = 1; off < 16; off <<= 1) {
                    float ov1 = __shfl_xor(v1, off); int oi1 = __shfl_xor(i1, off);
                    float ov2 = __shfl_xor(v2, off); int oi2 = __shfl_xor(i2, off);
                    if (ov1 > v1 || (ov1 == v1 && oi1 < i1)) {
                        float nv2; int ni2; pick_better(v1, i1, ov2, oi2, nv2, ni2);
                        v1 = ov1; i1 = oi1; v2 = nv2; i2 = ni2;
                    } else {
                        float nv2; int ni2; pick_better(v2, i2, ov1, oi1, nv2, ni2);
                        v2 = nv2; i2 = ni2;
                    }
                }
                if (cidx == 0) {
                    Top2 p; p.v1 = v1; p.i1 = i1; p.v2 = v2; p.i2 = i2;
                    mrg[wm * 64 + m * 16 + rgrp * 4 + j][wn] = p;
                }
            }
        }
        __syncthreads();
        if (tid < 256) {   // merge the two 64-code halves of each 128-code tile
            const int row = tid & 127, tau = tid >> 7;
            Top2 x0 = mrg[row][tau * 2], x1 = mrg[row][tau * 2 + 1];
            float v1 = x0.v1, v2 = x0.v2; int i1 = x0.i1, i2 = x0.i2;
            top2_insert(x1.v1, x1.i1, v1, i1, v2, i2);
            top2_insert(x1.v2, x1.i2, v1, i1, v2, i2);
            Top2 p; p.v1 = v1; p.i1 = i1; p.v2 = v2; p.i2 = i2;
            part[(size_t)(rb0 + row) * NTB + cgrp * 8 + p4 * 2 + tau] = p;
        }
        __syncthreads();   // mrg region free before next position's B writes
    }
#undef ITER
#undef BLOAD
}

// Per row: exact fp32 re-dot of candidates within MARGIN of the bf16 max, argmax,
// residual update (fp32 chain via out_stack + bf16 mirror), per-block loss partial
// (no atomics), usage; layer NL-1 also writes quantized = x - r.
__global__ __launch_bounds__(256)
void k_refine(const Top2* __restrict__ part, const float* __restrict__ CB,
              const float* __restrict__ prevBase, size_t prevStride,
              const float* __restrict__ X, float* __restrict__ out_q,
              float* __restrict__ stack, u16* __restrict__ residb,
              float* __restrict__ out_usage, float* __restrict__ pl,
              int layer)
{
    __shared__ float row[DD];
    __shared__ float candV[64];
    __shared__ int   candI[64];
    __shared__ float s_thr;
    __shared__ float wbv[4];
    __shared__ int   wbi[4];
    __shared__ int   s_best;
    __shared__ float red[256];

    const int b = blockIdx.x;
    const int tid = threadIdx.x;
    const float* pr = prevBase + (size_t)b * prevStride;
    row[tid]       = pr[tid];
    row[tid + 256] = pr[tid + 256];
    if (tid < 64) {
        Top2 p = part[(size_t)b * NTB + (tid >> 1)];
        candV[tid] = (tid & 1) ? p.v2 : p.v1;
        candI[tid] = (tid & 1) ? p.i2 : p.i1;
    }
    __syncthreads();
    if (tid < 64) {
        float v = candV[tid];
        for (int off = 1; off < 64; off <<= 1) v = fmaxf(v, __shfl_xor(v, off));
        if (tid == 0) s_thr = v - MARGIN;
    }
    __syncthreads();
    const float thr = s_thr;

    const int wave = tid >> 6;
    const int lane = tid & 63;
    float bestV = -INFINITY;
    int   bestI = 0x7fffffff;
    for (int s = 0; s < 16; ++s) {
        const int c = wave * 16 + s;
        if (candV[c] < thr) continue;          // wave-uniform skip
        const int ci = candI[c];
        const float* cr = CB + (size_t)ci * DD;
        float p = 0.f;
#pragma unroll
        for (int q = 0; q < 8; ++q)
            p = fmaf(row[lane * 8 + q], cr[lane * 8 + q], p);
        for (int off = 32; off >= 1; off >>= 1) p += __shfl_xor(p, off);
        if (p > bestV || (p == bestV && ci < bestI)) { bestV = p; bestI = ci; }
    }
    if (lane == 0) { wbv[wave] = bestV; wbi[wave] = bestI; }
    __syncthreads();
    if (tid == 0) {
        float bv = wbv[0]; int bi = wbi[0];
        for (int k = 1; k < 4; ++k)
            if (wbv[k] > bv || (wbv[k] == bv && wbi[k] < bi)) { bv = wbv[k]; bi = wbi[k]; }
        s_best = bi;
        out_usage[layer * KC + bi] = 1.0f;
    }
    __syncthreads();
    const int bi = s_best;

    const float* cr = CB + (size_t)bi * DD;
    const float rn0 = row[tid]       - cr[tid];
    const float rn1 = row[tid + 256] - cr[tid + 256];
    float* sp = stack + ((size_t)b * NL + layer) * DD;   // base odd-aligned -> scalar
    sp[tid]       = rn0;
    sp[tid + 256] = rn1;
    residb[(size_t)b * DD + tid]       = f2bf(rn0);
    residb[(size_t)b * DD + tid + 256] = f2bf(rn1);
    if (layer == NL - 1) {
        out_q[(size_t)b * DD + tid]       = X[(size_t)b * DD + tid]       - rn0;
        out_q[(size_t)b * DD + tid + 256] = X[(size_t)b * DD + tid + 256] - rn1;
    }
    red[tid] = rn0 * rn0 + rn1 * rn1;
    __syncthreads();
    for (int st = 128; st > 0; st >>= 1) {
        if (tid < st) red[tid] += red[tid + st];
        __syncthreads();
    }
    if (tid == 0) pl[(size_t)layer * NB + b] = red[0];
}

__global__ __launch_bounds__(256)
void k_cbsq(const float* __restrict__ cb, double* __restrict__ cq)
{
    __shared__ double red[256];
    const size_t n = (size_t)NL * KC * DD;
    double s = 0.0;
    for (size_t i = (size_t)blockIdx.x * blockDim.x + threadIdx.x; i < n;
         i += (size_t)gridDim.x * blockDim.x) {
        const float v = cb[i];
        s += (double)v * (double)v;
    }
    red[threadIdx.x] = s;
    __syncthreads();
    for (int st = 128; st > 0; st >>= 1) {
        if (threadIdx.x < st) red[threadIdx.x] += red[threadIdx.x + st];
        __syncthreads();
    }
    if (threadIdx.x == 0) cq[blockIdx.x] = red[0];
}

__global__ __launch_bounds__(256)
void k_finalize(const float* __restrict__ pl, const double* __restrict__ cq,
                float* __restrict__ out_loss)
{
    __shared__ double red[256];
    const int tid = threadIdx.x;
    double s = 0.0;
    for (int i = tid; i < NL * NB; i += 256) s += (double)pl[i];
    double s2 = 0.0;
    for (int i = tid; i < 1024; i += 256) s2 += cq[i];
    red[tid] = s / ((double)NB * DD) + 0.01 * (s2 / ((double)NL * KC));
    __syncthreads();
    for (int st = 128; st > 0; st >>= 1) {
        if (tid < st) red[tid] += red[tid + st];
        __syncthreads();
    }
    if (tid == 0) out_loss[0] = (float)(red[0] / (double)DD);
}

extern "C" void kernel_launch(void* const* d_in, const int* in_sizes, int n_in,
                              void* d_out, int out_size, void* d_ws, size_t ws_size,
                              hipStream_t stream)
{
    (void)in_sizes; (void)n_in; (void)out_size; (void)ws_size;
    const float* x  = (const float*)d_in[0];
    // d_in[1] = temperature: positive scale, argmax-invariant, soft path cancels -> unused
    const float* cb = (const float*)d_in[2];

    float* out       = (float*)d_out;
    float* out_q     = out;                                   // [NB, DD]
    float* out_loss  = out + (size_t)NB * DD;                 // [1]
    float* out_stack = out_loss + 1;                          // [NB, NL, DD] (fp32 residual chain)
    float* out_usage = out_stack + (size_t)NB * NL * DD;      // [NL, KC]

    char* ws = (char*)d_ws;
    Top2*  part   = (Top2*)ws;                                // 4 MB
    u16*   residb = (u16*)(ws + ((size_t)4 << 20));           // 8 MB bf16 residual mirror
    u16*   cbb    = (u16*)(ws + ((size_t)12 << 20));          // 4 MB bf16 codebook (per layer)
    float* pl     = (float*)(ws + ((size_t)16 << 20));        // NL*NB loss partials (128 KB)
    double* cq    = (double*)(ws + ((size_t)16 << 20) + 131072 + 256); // 1024 cbsq partials

    hipFuncSetAttribute((const void*)k_simtop2,
                        hipFuncAttributeMaxDynamicSharedMemorySize, 163840);

    hipMemsetAsync(out_usage, 0, (size_t)NL * KC * sizeof(float), stream);

    k_cvt_bf16<<<(NB * DD / 4 + 255) / 256, 256, 0, stream>>>(x, residb, NB * DD / 4);
    k_cbsq<<<1024, 256, 0, stream>>>(cb, cq);

    for (int l = 0; l < NL; ++l) {
        const float* cbl = cb + (size_t)l * KC * DD;
        k_cvt_bf16<<<(KC * DD / 4 + 255) / 256, 256, 0, stream>>>(cbl, cbb, KC * DD / 4);
        k_simtop2<<<256, 512, 163840, stream>>>(residb, cbb, part);
        const float* prevBase = (l == 0) ? x : (out_stack + (size_t)(l - 1) * DD);
        const size_t prevStride = (l == 0) ? (size_t)DD : (size_t)NL * DD;
        k_refine<<<NB, 256, 0, stream>>>(part, cbl, prevBase, prevStride, x, out_q,
                                         out_stack, residb, out_usage, pl, l);
    }
    k_finalize<<<1, 256, 0, stream>>>(pl, cq, out_loss);
}